// Round 11
// baseline (87.331 us; speedup 1.0000x reference)
//
#include <hip/hip_runtime.h>
#include <math.h>

#define BB 32
#define TT 1024
#define JJ 128
#define DD 256

typedef unsigned short u16;
typedef short s16x8 __attribute__((ext_vector_type(8)));
typedef float f32x4 __attribute__((ext_vector_type(4)));

#define MFMA_BF16(a, b, c) __builtin_amdgcn_mfma_f32_16x16x32_bf16((a), (b), (c), 0, 0, 0)

__device__ inline u16 f2bf(float f) {
    unsigned int u = __float_as_uint(f);
    u += 0x7FFFu + ((u >> 16) & 1u);
    return (u16)(u >> 16);
}
__device__ inline float bf2f(u16 h) {
    return __uint_as_float(((unsigned int)h) << 16);
}

// ---------------------------------------------------------------------------
// K2 (split-bf16 MFMA): S = ch + qu + (C*w_hu)·Q^T via hi/lo decomposition.
// Self-contained: B staged from fp32 Q inline (hi/lo + qu dot); ch inline;
// emits Cbf, Xg (= X·rowrcp, pre-scaled for k_out), Xt (raw X for k_tmp),
// Qt (bx<4 transpose of staged Bh), and writes the exact-fp32 C-passthrough
// section of the output directly from the staging registers.
// id = bx*32 + b -> id%8 = b%8 (XCD owns batch).
// ---------------------------------------------------------------------------
__global__ __launch_bounds__(256) void k_S(const float* __restrict__ C,
                                           const float* __restrict__ Q,
                                           const float* __restrict__ w,
                                           u16* __restrict__ Xg,
                                           u16* __restrict__ Xt,
                                           u16* __restrict__ Cbf,
                                           u16* __restrict__ Qt,
                                           float* __restrict__ rowmax,
                                           float* __restrict__ pm,
                                           float* __restrict__ ps,
                                           float* __restrict__ out) {
    const int id = blockIdx.x;
    const int b  = id & 31;
    const int bx = id >> 5;
    const int t0 = bx * 64;
    const int tid = threadIdx.x;

    union SMem {
        struct { u16 Ah[64 * 72]; u16 Al[64 * 72]; u16 Bh[128 * 72]; u16 Bl[128 * 72]; } g;
        struct { float S[64 * 132]; float RM[64]; float W[4]; float ER[64]; float PS2[256]; } e;
    };
    __shared__ __align__(16) SMem sm;
    __shared__ float sCH[64];
    __shared__ float sQU[128];

    const float* whu = w + 2 * DD;
    const float* Cb  = C + ((size_t)b * TT + t0) * DD;
    const float* Qb  = Q + (size_t)b * JJ * DD;

    const int lane = tid & 63, wv = tid >> 6;
    const int wm = wv >> 1, wn = wv & 1;
    const int lr = lane & 15, lg = lane >> 4;

    f32x4 zero4 = {0.f, 0.f, 0.f, 0.f};
    f32x4 acc[2][4];
    #pragma unroll
    for (int m = 0; m < 2; m++)
        #pragma unroll
        for (int n = 0; n < 4; n++) acc[m][n] = zero4;

    const int tA = tid >> 2, sA = (tid & 3) * 16;
    const int jB = tid >> 1, sB = (tid & 1) * 32;
    float chdot = 0.f;
    float qdot  = 0.f;

    for (int kc = 0; kc < DD; kc += 64) {
        __syncthreads();
        {   // stage A: (C*w_hu)[64t][64k] -> hi/lo bf16; ch dot; Cbf write;
            // exact-fp32 C-passthrough to out
            const float* cp  = Cb + (size_t)tA * DD + kc + sA;
            const float* wp  = whu + kc + sA;
            const float* whp = w + kc + sA;
            float cc[16], ww[16], wh[16];
            #pragma unroll
            for (int q = 0; q < 4; q++) {
                *(float4*)&cc[q * 4] = *(const float4*)(cp + q * 4);
                *(float4*)&ww[q * 4] = *(const float4*)(wp + q * 4);
                *(float4*)&wh[q * 4] = *(const float4*)(whp + q * 4);
            }
            u16 hi16[16], lo16[16], cb16[16];
            #pragma unroll
            for (int u = 0; u < 16; u++) {
                chdot += cc[u] * wh[u];
                cb16[u] = f2bf(cc[u]);
                float v = cc[u] * ww[u];
                u16 h = f2bf(v);
                hi16[u] = h;
                lo16[u] = f2bf(v - bf2f(h));
            }
            float* outp = out + ((size_t)(b * TT + t0 + tA)) * (4 * DD) + kc + sA;
            #pragma unroll
            for (int q = 0; q < 4; q++) *(float4*)(outp + q * 4) = *(float4*)&cc[q * 4];
            u16* cbp = &Cbf[((size_t)b * TT + t0 + tA) * DD + kc + sA];
            *(uint4*)&cbp[0] = *(uint4*)&cb16[0];
            *(uint4*)&cbp[8] = *(uint4*)&cb16[8];
            int o = tA * 72 + sA;
            *(uint4*)&sm.g.Ah[o]     = *(uint4*)&hi16[0];
            *(uint4*)&sm.g.Ah[o + 8] = *(uint4*)&hi16[8];
            *(uint4*)&sm.g.Al[o]     = *(uint4*)&lo16[0];
            *(uint4*)&sm.g.Al[o + 8] = *(uint4*)&lo16[8];
        }
        {   // stage B: Q[128j][64k] fp32 -> hi/lo bf16; qu dot inline
            const float* qp  = Qb + (size_t)jB * DD + kc + sB;
            const float* wup = w + DD + kc + sB;
            float qq[32], wu[32];
            #pragma unroll
            for (int q = 0; q < 8; q++) {
                *(float4*)&qq[q * 4] = *(const float4*)(qp + q * 4);
                *(float4*)&wu[q * 4] = *(const float4*)(wup + q * 4);
            }
            u16 h16[32], l16[32];
            #pragma unroll
            for (int u = 0; u < 32; u++) {
                qdot += qq[u] * wu[u];
                u16 h = f2bf(qq[u]);
                h16[u] = h;
                l16[u] = f2bf(qq[u] - bf2f(h));
            }
            uint4* dh = (uint4*)&sm.g.Bh[jB * 72 + sB];
            uint4* dl = (uint4*)&sm.g.Bl[jB * 72 + sB];
            #pragma unroll
            for (int q = 0; q < 4; q++) { dh[q] = *(uint4*)&h16[q * 8]; dl[q] = *(uint4*)&l16[q * 8]; }
        }
        __syncthreads();
        #pragma unroll
        for (int ks = 0; ks < 2; ks++) {
            const int ko = ks * 32 + lg * 8;
            s16x8 ah[2], al[2], bh[4], bl[4];
            #pragma unroll
            for (int m = 0; m < 2; m++) {
                ah[m] = *(const s16x8*)&sm.g.Ah[(wm * 32 + m * 16 + lr) * 72 + ko];
                al[m] = *(const s16x8*)&sm.g.Al[(wm * 32 + m * 16 + lr) * 72 + ko];
            }
            #pragma unroll
            for (int n = 0; n < 4; n++) {
                bh[n] = *(const s16x8*)&sm.g.Bh[(wn * 64 + n * 16 + lr) * 72 + ko];
                bl[n] = *(const s16x8*)&sm.g.Bl[(wn * 64 + n * 16 + lr) * 72 + ko];
            }
            #pragma unroll
            for (int m = 0; m < 2; m++)
                #pragma unroll
                for (int n = 0; n < 4; n++) {
                    f32x4 t = acc[m][n];
                    t = MFMA_BF16(ah[m], bh[n], t);
                    t = MFMA_BF16(ah[m], bl[n], t);
                    t = MFMA_BF16(al[m], bh[n], t);
                    acc[m][n] = t;
                }
        }
        // Qt emission: block bx == kc/64 transposes Bh [128j][64k] -> Qt [d][j]
        if (bx == (kc >> 6)) {
            int dloc = tid >> 2;
            int j0 = (tid & 3) * 32;
            u16 qb[32];
            #pragma unroll
            for (int u = 0; u < 32; u++) qb[u] = sm.g.Bh[(j0 + u) * 72 + dloc];
            u16* qtp = &Qt[((size_t)b * DD + kc + dloc) * JJ + j0];
            #pragma unroll
            for (int q = 0; q < 4; q++) *(uint4*)&qtp[q * 8] = *(uint4*)&qb[q * 8];
        }
    }

    // finalize ch and qu
    chdot += __shfl_xor(chdot, 1, 64);
    chdot += __shfl_xor(chdot, 2, 64);
    if ((tid & 3) == 0) sCH[tid >> 2] = chdot;
    float qd = qdot + __shfl_xor(qdot, 1, 64);
    if ((tid & 1) == 0) sQU[tid >> 1] = qd;

    // ---- epilogue ----
    __syncthreads();
    #pragma unroll
    for (int m = 0; m < 2; m++) {
        int row0 = wm * 32 + m * 16 + lg * 4;
        #pragma unroll
        for (int n = 0; n < 4; n++) {
            int col = wn * 64 + n * 16 + lr;
            float qv = sQU[col];
            #pragma unroll
            for (int reg = 0; reg < 4; reg++)
                sm.e.S[(row0 + reg) * 132 + col] = acc[m][n][reg] + sCH[row0 + reg] + qv;
        }
    }
    __syncthreads();
    {   // pass 1: row stats + in-place exp (S -> X fp32) + Xg = X*rowrcp direct
        int r = tid >> 2, s = tid & 3;
        float v[32];
        float* Sr = &sm.e.S[r * 132 + s * 32];
        #pragma unroll
        for (int q = 0; q < 8; q++) *(float4*)&v[q * 4] = *(const float4*)&Sr[q * 4];
        float mx = v[0];
        #pragma unroll
        for (int u = 1; u < 32; u++) mx = fmaxf(mx, v[u]);
        mx = fmaxf(mx, __shfl_xor(mx, 1, 64));
        mx = fmaxf(mx, __shfl_xor(mx, 2, 64));
        float sum = 0.f;
        #pragma unroll
        for (int u = 0; u < 32; u++) { v[u] = __expf(v[u] - mx); sum += v[u]; }
        sum += __shfl_xor(sum, 1, 64);
        sum += __shfl_xor(sum, 2, 64);
        #pragma unroll
        for (int q = 0; q < 8; q++) *(float4*)&Sr[q * 4] = *(const float4*)&v[q * 4];
        float rcp = 1.0f / sum;
        u16 xp[32];
        #pragma unroll
        for (int u = 0; u < 32; u++) xp[u] = f2bf(v[u] * rcp);
        u16* xgp = &Xg[((size_t)b * TT + t0 + r) * JJ + s * 32];
        #pragma unroll
        for (int q = 0; q < 4; q++) *(uint4*)&xgp[q * 8] = *(uint4*)&xp[q * 8];
        if (s == 0) {
            sm.e.RM[r] = mx;
            rowmax[(size_t)b * TT + t0 + r] = mx;
        }
        float wmx = mx;
        wmx = fmaxf(wmx, __shfl_xor(wmx, 4, 64));
        wmx = fmaxf(wmx, __shfl_xor(wmx, 8, 64));
        wmx = fmaxf(wmx, __shfl_xor(wmx, 16, 64));
        wmx = fmaxf(wmx, __shfl_xor(wmx, 32, 64));
        if (lane == 0) sm.e.W[wv] = wmx;
    }
    __syncthreads();
    const float Mb = fmaxf(fmaxf(sm.e.W[0], sm.e.W[1]), fmaxf(sm.e.W[2], sm.e.W[3]));
    if (tid < 64) sm.e.ER[tid] = __expf(sm.e.RM[tid] - Mb);
    // Xt write [j][t] (raw X for k_tmp): thread = (j, 32-t seg)
    {
        int j = tid & 127, seg = tid >> 7;
        u16 xb[32];
        #pragma unroll
        for (int k = 0; k < 32; k++)
            xb[k] = f2bf(sm.e.S[(seg * 32 + k) * 132 + j]);
        u16* xtp = &Xt[((size_t)b * JJ + j) * TT + t0 + seg * 32];
        #pragma unroll
        for (int q = 0; q < 4; q++) *(uint4*)&xtp[q * 8] = *(uint4*)&xb[q * 8];
    }
    __syncthreads();
    {   // column partials: pure fma against ER (no exp)
        int j = tid & 127, h = tid >> 7;
        float cs = 0.f;
        #pragma unroll
        for (int k = 0; k < 32; k++)
            cs = fmaf(sm.e.S[(h * 32 + k) * 132 + j], sm.e.ER[h * 32 + k], cs);
        sm.e.PS2[h * 128 + j] = cs;
    }
    __syncthreads();
    if (tid < 128) ps[((size_t)b * 16 + bx) * JJ + tid] = sm.e.PS2[tid] + sm.e.PS2[128 + tid];
    if (tid == 0)  pm[b * 16 + bx] = Mb;
}

// ---------------------------------------------------------------------------
// K4 (MFMA): Tt[d,j] = ec[j] * sum_t X[t,j] * (er[t]*C[t,d]).
// er folded into C'-staging; ec into epilogue; G-staging = pure uint4 copies.
// id%8 = b%8 (XCD owns batch).
// ---------------------------------------------------------------------------
__global__ __launch_bounds__(256) void k_tmp(const u16* __restrict__ Xt,
                                             const u16* __restrict__ Cbf,
                                             const float* __restrict__ rowmax,
                                             const float* __restrict__ pm,
                                             const float* __restrict__ ps,
                                             u16* __restrict__ Tt) {
    const int id = blockIdx.x;
    const int b = id & 31, dh = id >> 5;          // dh in 0..7
    const int d0 = dh * 32;
    const int tid = threadIdx.x;
    __shared__ __align__(16) u16 sG[128 * 72];    // [j][t] stride 72 (pure X)
    __shared__ __align__(16) u16 sCt[32 * 72];    // [d][t] stride 72 (er*C)
    __shared__ float sER[1024];
    __shared__ float sEC[128];
    __shared__ float sPE[16];
    __shared__ float sW2[4];
    const int lane = tid & 63, wv = tid >> 6;

    {   // K_b = max rowmax over batch; er, ec = 1/colsum(K-ref)
        float4 rm4 = *(const float4*)&rowmax[(size_t)b * TT + tid * 4];
        float km = fmaxf(fmaxf(rm4.x, rm4.y), fmaxf(rm4.z, rm4.w));
        #pragma unroll
        for (int off = 1; off < 64; off <<= 1) km = fmaxf(km, __shfl_xor(km, off, 64));
        if (lane == 0) sW2[wv] = km;
        __syncthreads();
        const float K = fmaxf(fmaxf(sW2[0], sW2[1]), fmaxf(sW2[2], sW2[3]));
        float4 e4;
        e4.x = __expf(rm4.x - K);
        e4.y = __expf(rm4.y - K);
        e4.z = __expf(rm4.z - K);
        e4.w = __expf(rm4.w - K);
        *(float4*)&sER[tid * 4] = e4;
        if (tid < 16) sPE[tid] = __expf(pm[b * 16 + tid] - K);
        __syncthreads();
        if (tid < 128) {
            float cy = 0.f;
            #pragma unroll
            for (int blk = 0; blk < 16; blk++)
                cy = fmaf(ps[((size_t)b * 16 + blk) * JJ + tid], sPE[blk], cy);
            sEC[tid] = 1.0f / cy;
        }
    }

    const int lr = lane & 15, lg = lane >> 4;
    f32x4 zero4 = {0.f, 0.f, 0.f, 0.f};
    f32x4 acc[2][2];
    acc[0][0] = zero4; acc[0][1] = zero4; acc[1][0] = zero4; acc[1][1] = zero4;

    const int gj = tid >> 1, gs = (tid & 1) * 32;     // G: j row, 32-t seg
    const int ct = tid & 63, cg = (tid >> 6) * 8;     // Ct: t row, 8-d seg

    for (int tt = 0; tt < TT; tt += 64) {
        __syncthreads();
        {   // stage G = X (pure uint4 copies from Xt)
            const u16* xtp = &Xt[((size_t)b * JJ + gj) * TT + tt + gs];
            u16* gp = &sG[gj * 72 + gs];
            #pragma unroll
            for (int q = 0; q < 4; q++) *(uint4*)&gp[q * 8] = *(const uint4*)&xtp[q * 8];
        }
        {   // stage C' = er[t]*C[t,d]
            float e = sER[tt + ct];
            uint4 cv = *(const uint4*)&Cbf[((size_t)b * TT + tt + ct) * DD + d0 + cg];
            const u16* cp = (const u16*)&cv;
            #pragma unroll
            for (int u = 0; u < 8; u++) sCt[(cg + u) * 72 + ct] = f2bf(bf2f(cp[u]) * e);
        }
        __syncthreads();
        #pragma unroll
        for (int ks = 0; ks < 2; ks++) {
            int ko = ks * 32 + lg * 8;
            s16x8 a0 = *(const s16x8*)&sG[(wv * 32 + lr) * 72 + ko];
            s16x8 a1 = *(const s16x8*)&sG[(wv * 32 + 16 + lr) * 72 + ko];
            s16x8 b0 = *(const s16x8*)&sCt[(lr) * 72 + ko];
            s16x8 b1 = *(const s16x8*)&sCt[(16 + lr) * 72 + ko];
            acc[0][0] = MFMA_BF16(a0, b0, acc[0][0]);
            acc[0][1] = MFMA_BF16(a0, b1, acc[0][1]);
            acc[1][0] = MFMA_BF16(a1, b0, acc[1][0]);
            acc[1][1] = MFMA_BF16(a1, b1, acc[1][1]);
        }
    }
    #pragma unroll
    for (int mr = 0; mr < 2; mr++)
        #pragma unroll
        for (int nr = 0; nr < 2; nr++)
            #pragma unroll
            for (int reg = 0; reg < 4; reg++) {
                int j = wv * 32 + mr * 16 + lg * 4 + reg;
                int d = d0 + nr * 16 + lr;
                Tt[((size_t)b * DD + d) * JJ + j] = f2bf(acc[mr][nr][reg] * sEC[j]);
            }
}

// ---------------------------------------------------------------------------
// K5 (MFMA): A = Xg·Q, Bm = Xg·tmp (Xg pre-scaled by rowrcp);
// out = [_, A, C*A, C*Bm] (C-passthrough already written by k_S).
// id = k*32 + b -> id%8 = b%8.
// ---------------------------------------------------------------------------
__global__ __launch_bounds__(256) void k_out(const u16* __restrict__ Xg,
                                             const u16* __restrict__ Qt,
                                             const u16* __restrict__ Tt,
                                             const u16* __restrict__ Cbf,
                                             float* __restrict__ out) {
    const int id = blockIdx.x;
    const int b = id & 31, k = id >> 5;
    const int dc = k & 3, tc = k >> 2;
    const int t0 = tc * 64, d0 = dc * 64;
    const int tid = threadIdx.x;
    __shared__ __align__(16) u16 sX[64 * 136];
    __shared__ __align__(16) u16 sQ[64 * 136];
    __shared__ __align__(16) u16 sT[64 * 136];
    const size_t xbase = ((size_t)b * TT + t0) * JJ;
    const size_t qbase = ((size_t)b * DD + d0) * JJ;
    #pragma unroll
    for (int i = 0; i < 4; i++) {
        int c = tid + 256 * i;
        int row = c >> 4, col = (c & 15) * 8;
        int lo = row * 136 + col;
        *(uint4*)&sX[lo] = *(const uint4*)&Xg[xbase + (size_t)row * JJ + col];
        *(uint4*)&sQ[lo] = *(const uint4*)&Qt[qbase + (size_t)row * JJ + col];
        *(uint4*)&sT[lo] = *(const uint4*)&Tt[qbase + (size_t)row * JJ + col];
    }
    __syncthreads();
    const int lane = tid & 63, wv = tid >> 6;
    const int wm = wv >> 1, wn = wv & 1;
    const int lr = lane & 15, lg = lane >> 4;
    f32x4 zero4 = {0.f, 0.f, 0.f, 0.f};
    f32x4 accA[2][2], accB[2][2];
    #pragma unroll
    for (int mr = 0; mr < 2; mr++)
        #pragma unroll
        for (int nr = 0; nr < 2; nr++) { accA[mr][nr] = zero4; accB[mr][nr] = zero4; }

    #pragma unroll
    for (int ks = 0; ks < 4; ks++) {
        int kc = ks * 32 + lg * 8;
        s16x8 a0 = *(const s16x8*)&sX[(wm * 32 + lr) * 136 + kc];
        s16x8 a1 = *(const s16x8*)&sX[(wm * 32 + 16 + lr) * 136 + kc];
        s16x8 q0 = *(const s16x8*)&sQ[(wn * 32 + lr) * 136 + kc];
        s16x8 q1 = *(const s16x8*)&sQ[(wn * 32 + 16 + lr) * 136 + kc];
        s16x8 u0 = *(const s16x8*)&sT[(wn * 32 + lr) * 136 + kc];
        s16x8 u1 = *(const s16x8*)&sT[(wn * 32 + 16 + lr) * 136 + kc];
        accA[0][0] = MFMA_BF16(a0, q0, accA[0][0]);
        accA[0][1] = MFMA_BF16(a0, q1, accA[0][1]);
        accA[1][0] = MFMA_BF16(a1, q0, accA[1][0]);
        accA[1][1] = MFMA_BF16(a1, q1, accA[1][1]);
        accB[0][0] = MFMA_BF16(a0, u0, accB[0][0]);
        accB[0][1] = MFMA_BF16(a0, u1, accB[0][1]);
        accB[1][0] = MFMA_BF16(a1, u0, accB[1][0]);
        accB[1][1] = MFMA_BF16(a1, u1, accB[1][1]);
    }

    #pragma unroll
    for (int mr = 0; mr < 2; mr++) {
        #pragma unroll
        for (int reg = 0; reg < 4; reg++) {
            int t = t0 + wm * 32 + mr * 16 + lg * 4 + reg;
            const u16* Cp = Cbf + ((size_t)b * TT + t) * DD;
            float* op = out + ((size_t)b * TT + t) * (4 * DD);
            #pragma unroll
            for (int nr = 0; nr < 2; nr++) {
                int d = d0 + wn * 32 + nr * 16 + lr;
                float cv = bf2f(Cp[d]);
                float av = accA[mr][nr][reg];
                float bv = accB[mr][nr][reg];
                op[DD + d]     = av;
                op[2 * DD + d] = cv * av;
                op[3 * DD + d] = cv * bv;
            }
        }
    }
}

// ---------------------------------------------------------------------------
extern "C" void kernel_launch(void* const* d_in, const int* in_sizes, int n_in,
                              void* d_out, int out_size, void* d_ws, size_t ws_size,
                              hipStream_t stream) {
    const float* C = (const float*)d_in[0];
    const float* Q = (const float*)d_in[1];
    const float* w = (const float*)d_in[2];
    float* out = (float*)d_out;
    float* p = (float*)d_ws;

    u16* Xg  = (u16*)p;     p += (size_t)BB * TT * JJ / 2;   // 8.4 MB (X*rowrcp)
    u16* Xt  = (u16*)p;     p += (size_t)BB * JJ * TT / 2;   // 8.4 MB (raw X)
    u16* Cbf = (u16*)p;     p += (size_t)BB * TT * DD / 2;   // 16.8 MB
    u16* Qt  = (u16*)p;     p += (size_t)BB * DD * JJ / 2;
    u16* Tt  = (u16*)p;     p += (size_t)BB * DD * JJ / 2;
    float* rowmax = p;      p += BB * TT;
    float* pm     = p;      p += BB * 16;
    float* ps     = p;      p += (size_t)BB * 16 * JJ;

    k_S     <<<dim3(16 * BB), dim3(256), 0, stream>>>(C, Q, w, Xg, Xt, Cbf, Qt, rowmax, pm, ps, out);
    k_tmp   <<<dim3(8 * BB), dim3(256), 0, stream>>>(Xt, Cbf, rowmax, pm, ps, Tt);
    k_out   <<<dim3(64 * BB), dim3(256), 0, stream>>>(Xg, Qt, Tt, Cbf, out);
}

// Round 12
// 83.668 us; speedup vs baseline: 1.0438x; 1.0438x over previous
//
#include <hip/hip_runtime.h>
#include <math.h>

#define BB 32
#define TT 1024
#define JJ 128
#define DD 256

typedef unsigned short u16;
typedef short s16x8 __attribute__((ext_vector_type(8)));
typedef float f32x4 __attribute__((ext_vector_type(4)));

#define MFMA_BF16(a, b, c) __builtin_amdgcn_mfma_f32_16x16x32_bf16((a), (b), (c), 0, 0, 0)

__device__ inline u16 f2bf(float f) {
    unsigned int u = __float_as_uint(f);
    u += 0x7FFFu + ((u >> 16) & 1u);
    return (u16)(u >> 16);
}
__device__ inline float bf2f(u16 h) {
    return __uint_as_float(((unsigned int)h) << 16);
}

// ---------------------------------------------------------------------------
// K2 (split-bf16 MFMA): S = ch + qu + (C*w_hu)·Q^T via hi/lo decomposition.
// Self-contained: B staged from fp32 Q inline (hi/lo + qu dot); ch inline;
// emits Cbf, Xg (= X·rowrcp, pre-scaled for k_out), Xt (raw X for k_tmp),
// Qt (bx==kc/64 transpose of staged Bh).
// id = bx*32 + b -> id%8 = b%8 (XCD owns batch).
// ---------------------------------------------------------------------------
__global__ __launch_bounds__(256) void k_S(const float* __restrict__ C,
                                           const float* __restrict__ Q,
                                           const float* __restrict__ w,
                                           u16* __restrict__ Xg,
                                           u16* __restrict__ Xt,
                                           u16* __restrict__ Cbf,
                                           u16* __restrict__ Qt,
                                           float* __restrict__ rowmax,
                                           float* __restrict__ pm,
                                           float* __restrict__ ps) {
    const int id = blockIdx.x;
    const int b  = id & 31;
    const int bx = id >> 5;
    const int t0 = bx * 64;
    const int tid = threadIdx.x;

    union SMem {
        struct { u16 Ah[64 * 72]; u16 Al[64 * 72]; u16 Bh[128 * 72]; u16 Bl[128 * 72]; } g;
        struct { float S[64 * 132]; float RM[64]; float W[4]; float ER[64]; float PS2[256]; } e;
    };
    __shared__ __align__(16) SMem sm;
    __shared__ float sCH[64];
    __shared__ float sQU[128];

    const float* whu = w + 2 * DD;
    const float* Cb  = C + ((size_t)b * TT + t0) * DD;
    const float* Qb  = Q + (size_t)b * JJ * DD;

    const int lane = tid & 63, wv = tid >> 6;
    const int wm = wv >> 1, wn = wv & 1;
    const int lr = lane & 15, lg = lane >> 4;

    f32x4 zero4 = {0.f, 0.f, 0.f, 0.f};
    f32x4 acc[2][4];
    #pragma unroll
    for (int m = 0; m < 2; m++)
        #pragma unroll
        for (int n = 0; n < 4; n++) acc[m][n] = zero4;

    const int tA = tid >> 2, sA = (tid & 3) * 16;
    const int jB = tid >> 1, sB = (tid & 1) * 32;
    float chdot = 0.f;
    float qdot  = 0.f;

    for (int kc = 0; kc < DD; kc += 64) {
        __syncthreads();
        {   // stage A: (C*w_hu)[64t][64k] -> hi/lo bf16; ch dot; Cbf write
            const float* cp  = Cb + (size_t)tA * DD + kc + sA;
            const float* wp  = whu + kc + sA;
            const float* whp = w + kc + sA;
            float cc[16], ww[16], wh[16];
            #pragma unroll
            for (int q = 0; q < 4; q++) {
                *(float4*)&cc[q * 4] = *(const float4*)(cp + q * 4);
                *(float4*)&ww[q * 4] = *(const float4*)(wp + q * 4);
                *(float4*)&wh[q * 4] = *(const float4*)(whp + q * 4);
            }
            u16 hi16[16], lo16[16], cb16[16];
            #pragma unroll
            for (int u = 0; u < 16; u++) {
                chdot += cc[u] * wh[u];
                cb16[u] = f2bf(cc[u]);
                float v = cc[u] * ww[u];
                u16 h = f2bf(v);
                hi16[u] = h;
                lo16[u] = f2bf(v - bf2f(h));
            }
            u16* cbp = &Cbf[((size_t)b * TT + t0 + tA) * DD + kc + sA];
            *(uint4*)&cbp[0] = *(uint4*)&cb16[0];
            *(uint4*)&cbp[8] = *(uint4*)&cb16[8];
            int o = tA * 72 + sA;
            *(uint4*)&sm.g.Ah[o]     = *(uint4*)&hi16[0];
            *(uint4*)&sm.g.Ah[o + 8] = *(uint4*)&hi16[8];
            *(uint4*)&sm.g.Al[o]     = *(uint4*)&lo16[0];
            *(uint4*)&sm.g.Al[o + 8] = *(uint4*)&lo16[8];
        }
        {   // stage B: Q[128j][64k] fp32 -> hi/lo bf16; qu dot inline
            const float* qp  = Qb + (size_t)jB * DD + kc + sB;
            const float* wup = w + DD + kc + sB;
            float qq[32], wu[32];
            #pragma unroll
            for (int q = 0; q < 8; q++) {
                *(float4*)&qq[q * 4] = *(const float4*)(qp + q * 4);
                *(float4*)&wu[q * 4] = *(const float4*)(wup + q * 4);
            }
            u16 h16[32], l16[32];
            #pragma unroll
            for (int u = 0; u < 32; u++) {
                qdot += qq[u] * wu[u];
                u16 h = f2bf(qq[u]);
                h16[u] = h;
                l16[u] = f2bf(qq[u] - bf2f(h));
            }
            uint4* dh = (uint4*)&sm.g.Bh[jB * 72 + sB];
            uint4* dl = (uint4*)&sm.g.Bl[jB * 72 + sB];
            #pragma unroll
            for (int q = 0; q < 4; q++) { dh[q] = *(uint4*)&h16[q * 8]; dl[q] = *(uint4*)&l16[q * 8]; }
        }
        __syncthreads();
        #pragma unroll
        for (int ks = 0; ks < 2; ks++) {
            const int ko = ks * 32 + lg * 8;
            s16x8 ah[2], al[2], bh[4], bl[4];
            #pragma unroll
            for (int m = 0; m < 2; m++) {
                ah[m] = *(const s16x8*)&sm.g.Ah[(wm * 32 + m * 16 + lr) * 72 + ko];
                al[m] = *(const s16x8*)&sm.g.Al[(wm * 32 + m * 16 + lr) * 72 + ko];
            }
            #pragma unroll
            for (int n = 0; n < 4; n++) {
                bh[n] = *(const s16x8*)&sm.g.Bh[(wn * 64 + n * 16 + lr) * 72 + ko];
                bl[n] = *(const s16x8*)&sm.g.Bl[(wn * 64 + n * 16 + lr) * 72 + ko];
            }
            #pragma unroll
            for (int m = 0; m < 2; m++)
                #pragma unroll
                for (int n = 0; n < 4; n++) {
                    f32x4 t = acc[m][n];
                    t = MFMA_BF16(ah[m], bh[n], t);
                    t = MFMA_BF16(ah[m], bl[n], t);
                    t = MFMA_BF16(al[m], bh[n], t);
                    acc[m][n] = t;
                }
        }
        // Qt emission: block bx == kc/64 transposes Bh [128j][64k] -> Qt [d][j]
        if (bx == (kc >> 6)) {
            int dloc = tid >> 2;
            int j0 = (tid & 3) * 32;
            u16 qb[32];
            #pragma unroll
            for (int u = 0; u < 32; u++) qb[u] = sm.g.Bh[(j0 + u) * 72 + dloc];
            u16* qtp = &Qt[((size_t)b * DD + kc + dloc) * JJ + j0];
            #pragma unroll
            for (int q = 0; q < 4; q++) *(uint4*)&qtp[q * 8] = *(uint4*)&qb[q * 8];
        }
    }

    // finalize ch and qu
    chdot += __shfl_xor(chdot, 1, 64);
    chdot += __shfl_xor(chdot, 2, 64);
    if ((tid & 3) == 0) sCH[tid >> 2] = chdot;
    float qd = qdot + __shfl_xor(qdot, 1, 64);
    if ((tid & 1) == 0) sQU[tid >> 1] = qd;

    // ---- epilogue ----
    __syncthreads();
    #pragma unroll
    for (int m = 0; m < 2; m++) {
        int row0 = wm * 32 + m * 16 + lg * 4;
        #pragma unroll
        for (int n = 0; n < 4; n++) {
            int col = wn * 64 + n * 16 + lr;
            float qv = sQU[col];
            #pragma unroll
            for (int reg = 0; reg < 4; reg++)
                sm.e.S[(row0 + reg) * 132 + col] = acc[m][n][reg] + sCH[row0 + reg] + qv;
        }
    }
    __syncthreads();
    {   // pass 1: row stats + in-place exp (S -> X fp32) + Xg = X*rowrcp direct
        int r = tid >> 2, s = tid & 3;
        float v[32];
        float* Sr = &sm.e.S[r * 132 + s * 32];
        #pragma unroll
        for (int q = 0; q < 8; q++) *(float4*)&v[q * 4] = *(const float4*)&Sr[q * 4];
        float mx = v[0];
        #pragma unroll
        for (int u = 1; u < 32; u++) mx = fmaxf(mx, v[u]);
        mx = fmaxf(mx, __shfl_xor(mx, 1, 64));
        mx = fmaxf(mx, __shfl_xor(mx, 2, 64));
        float sum = 0.f;
        #pragma unroll
        for (int u = 0; u < 32; u++) { v[u] = __expf(v[u] - mx); sum += v[u]; }
        sum += __shfl_xor(sum, 1, 64);
        sum += __shfl_xor(sum, 2, 64);
        #pragma unroll
        for (int q = 0; q < 8; q++) *(float4*)&Sr[q * 4] = *(const float4*)&v[q * 4];
        float rcp = 1.0f / sum;
        u16 xp[32];
        #pragma unroll
        for (int u = 0; u < 32; u++) xp[u] = f2bf(v[u] * rcp);
        u16* xgp = &Xg[((size_t)b * TT + t0 + r) * JJ + s * 32];
        #pragma unroll
        for (int q = 0; q < 4; q++) *(uint4*)&xgp[q * 8] = *(uint4*)&xp[q * 8];
        if (s == 0) {
            sm.e.RM[r] = mx;
            rowmax[(size_t)b * TT + t0 + r] = mx;
        }
        float wmx = mx;
        wmx = fmaxf(wmx, __shfl_xor(wmx, 4, 64));
        wmx = fmaxf(wmx, __shfl_xor(wmx, 8, 64));
        wmx = fmaxf(wmx, __shfl_xor(wmx, 16, 64));
        wmx = fmaxf(wmx, __shfl_xor(wmx, 32, 64));
        if (lane == 0) sm.e.W[wv] = wmx;
    }
    __syncthreads();
    const float Mb = fmaxf(fmaxf(sm.e.W[0], sm.e.W[1]), fmaxf(sm.e.W[2], sm.e.W[3]));
    if (tid < 64) sm.e.ER[tid] = __expf(sm.e.RM[tid] - Mb);
    // Xt write [j][t] (raw X for k_tmp): thread = (j, 32-t seg)
    {
        int j = tid & 127, seg = tid >> 7;
        u16 xb[32];
        #pragma unroll
        for (int k = 0; k < 32; k++)
            xb[k] = f2bf(sm.e.S[(seg * 32 + k) * 132 + j]);
        u16* xtp = &Xt[((size_t)b * JJ + j) * TT + t0 + seg * 32];
        #pragma unroll
        for (int q = 0; q < 4; q++) *(uint4*)&xtp[q * 8] = *(uint4*)&xb[q * 8];
    }
    __syncthreads();
    {   // column partials: pure fma against ER (no exp)
        int j = tid & 127, h = tid >> 7;
        float cs = 0.f;
        #pragma unroll
        for (int k = 0; k < 32; k++)
            cs = fmaf(sm.e.S[(h * 32 + k) * 132 + j], sm.e.ER[h * 32 + k], cs);
        sm.e.PS2[h * 128 + j] = cs;
    }
    __syncthreads();
    if (tid < 128) ps[((size_t)b * 16 + bx) * JJ + tid] = sm.e.PS2[tid] + sm.e.PS2[128 + tid];
    if (tid == 0)  pm[b * 16 + bx] = Mb;
}

// ---------------------------------------------------------------------------
// K4 (MFMA): Tt[d,j] = ec[j] * sum_t X[t,j] * (er[t]*C[t,d]).
// er folded into C'-staging; ec into epilogue; G-staging = pure uint4 copies.
// id%8 = b%8 (XCD owns batch).
// ---------------------------------------------------------------------------
__global__ __launch_bounds__(256) void k_tmp(const u16* __restrict__ Xt,
                                             const u16* __restrict__ Cbf,
                                             const float* __restrict__ rowmax,
                                             const float* __restrict__ pm,
                                             const float* __restrict__ ps,
                                             u16* __restrict__ Tt) {
    const int id = blockIdx.x;
    const int b = id & 31, dh = id >> 5;          // dh in 0..7
    const int d0 = dh * 32;
    const int tid = threadIdx.x;
    __shared__ __align__(16) u16 sG[128 * 72];    // [j][t] stride 72 (pure X)
    __shared__ __align__(16) u16 sCt[32 * 72];    // [d][t] stride 72 (er*C)
    __shared__ float sER[1024];
    __shared__ float sEC[128];
    __shared__ float sPE[16];
    __shared__ float sW2[4];
    const int lane = tid & 63, wv = tid >> 6;

    {   // K_b = max rowmax over batch; er, ec = 1/colsum(K-ref)
        float4 rm4 = *(const float4*)&rowmax[(size_t)b * TT + tid * 4];
        float km = fmaxf(fmaxf(rm4.x, rm4.y), fmaxf(rm4.z, rm4.w));
        #pragma unroll
        for (int off = 1; off < 64; off <<= 1) km = fmaxf(km, __shfl_xor(km, off, 64));
        if (lane == 0) sW2[wv] = km;
        __syncthreads();
        const float K = fmaxf(fmaxf(sW2[0], sW2[1]), fmaxf(sW2[2], sW2[3]));
        float4 e4;
        e4.x = __expf(rm4.x - K);
        e4.y = __expf(rm4.y - K);
        e4.z = __expf(rm4.z - K);
        e4.w = __expf(rm4.w - K);
        *(float4*)&sER[tid * 4] = e4;
        if (tid < 16) sPE[tid] = __expf(pm[b * 16 + tid] - K);
        __syncthreads();
        if (tid < 128) {
            float cy = 0.f;
            #pragma unroll
            for (int blk = 0; blk < 16; blk++)
                cy = fmaf(ps[((size_t)b * 16 + blk) * JJ + tid], sPE[blk], cy);
            sEC[tid] = 1.0f / cy;
        }
    }

    const int lr = lane & 15, lg = lane >> 4;
    f32x4 zero4 = {0.f, 0.f, 0.f, 0.f};
    f32x4 acc[2][2];
    acc[0][0] = zero4; acc[0][1] = zero4; acc[1][0] = zero4; acc[1][1] = zero4;

    const int gj = tid >> 1, gs = (tid & 1) * 32;     // G: j row, 32-t seg
    const int ct = tid & 63, cg = (tid >> 6) * 8;     // Ct: t row, 8-d seg

    for (int tt = 0; tt < TT; tt += 64) {
        __syncthreads();
        {   // stage G = X (pure uint4 copies from Xt)
            const u16* xtp = &Xt[((size_t)b * JJ + gj) * TT + tt + gs];
            u16* gp = &sG[gj * 72 + gs];
            #pragma unroll
            for (int q = 0; q < 4; q++) *(uint4*)&gp[q * 8] = *(const uint4*)&xtp[q * 8];
        }
        {   // stage C' = er[t]*C[t,d]
            float e = sER[tt + ct];
            uint4 cv = *(const uint4*)&Cbf[((size_t)b * TT + tt + ct) * DD + d0 + cg];
            const u16* cp = (const u16*)&cv;
            #pragma unroll
            for (int u = 0; u < 8; u++) sCt[(cg + u) * 72 + ct] = f2bf(bf2f(cp[u]) * e);
        }
        __syncthreads();
        #pragma unroll
        for (int ks = 0; ks < 2; ks++) {
            int ko = ks * 32 + lg * 8;
            s16x8 a0 = *(const s16x8*)&sG[(wv * 32 + lr) * 72 + ko];
            s16x8 a1 = *(const s16x8*)&sG[(wv * 32 + 16 + lr) * 72 + ko];
            s16x8 b0 = *(const s16x8*)&sCt[(lr) * 72 + ko];
            s16x8 b1 = *(const s16x8*)&sCt[(16 + lr) * 72 + ko];
            acc[0][0] = MFMA_BF16(a0, b0, acc[0][0]);
            acc[0][1] = MFMA_BF16(a0, b1, acc[0][1]);
            acc[1][0] = MFMA_BF16(a1, b0, acc[1][0]);
            acc[1][1] = MFMA_BF16(a1, b1, acc[1][1]);
        }
    }
    #pragma unroll
    for (int mr = 0; mr < 2; mr++)
        #pragma unroll
        for (int nr = 0; nr < 2; nr++)
            #pragma unroll
            for (int reg = 0; reg < 4; reg++) {
                int j = wv * 32 + mr * 16 + lg * 4 + reg;
                int d = d0 + nr * 16 + lr;
                Tt[((size_t)b * DD + d) * JJ + j] = f2bf(acc[mr][nr][reg] * sEC[j]);
            }
}

// ---------------------------------------------------------------------------
// K5 (MFMA): A = Xg·Q, Bm = Xg·tmp (Xg pre-scaled by rowrcp);
// out = [C, A, C*A, C*Bm]; C from Cbf. id = k*32 + b -> id%8 = b%8.
// ---------------------------------------------------------------------------
__global__ __launch_bounds__(256) void k_out(const u16* __restrict__ Xg,
                                             const u16* __restrict__ Qt,
                                             const u16* __restrict__ Tt,
                                             const u16* __restrict__ Cbf,
                                             float* __restrict__ out) {
    const int id = blockIdx.x;
    const int b = id & 31, k = id >> 5;
    const int dc = k & 3, tc = k >> 2;
    const int t0 = tc * 64, d0 = dc * 64;
    const int tid = threadIdx.x;
    __shared__ __align__(16) u16 sX[64 * 136];
    __shared__ __align__(16) u16 sQ[64 * 136];
    __shared__ __align__(16) u16 sT[64 * 136];
    const size_t xbase = ((size_t)b * TT + t0) * JJ;
    const size_t qbase = ((size_t)b * DD + d0) * JJ;
    #pragma unroll
    for (int i = 0; i < 4; i++) {
        int c = tid + 256 * i;
        int row = c >> 4, col = (c & 15) * 8;
        int lo = row * 136 + col;
        *(uint4*)&sX[lo] = *(const uint4*)&Xg[xbase + (size_t)row * JJ + col];
        *(uint4*)&sQ[lo] = *(const uint4*)&Qt[qbase + (size_t)row * JJ + col];
        *(uint4*)&sT[lo] = *(const uint4*)&Tt[qbase + (size_t)row * JJ + col];
    }
    __syncthreads();
    const int lane = tid & 63, wv = tid >> 6;
    const int wm = wv >> 1, wn = wv & 1;
    const int lr = lane & 15, lg = lane >> 4;
    f32x4 zero4 = {0.f, 0.f, 0.f, 0.f};
    f32x4 accA[2][2], accB[2][2];
    #pragma unroll
    for (int mr = 0; mr < 2; mr++)
        #pragma unroll
        for (int nr = 0; nr < 2; nr++) { accA[mr][nr] = zero4; accB[mr][nr] = zero4; }

    #pragma unroll
    for (int ks = 0; ks < 4; ks++) {
        int kc = ks * 32 + lg * 8;
        s16x8 a0 = *(const s16x8*)&sX[(wm * 32 + lr) * 136 + kc];
        s16x8 a1 = *(const s16x8*)&sX[(wm * 32 + 16 + lr) * 136 + kc];
        s16x8 q0 = *(const s16x8*)&sQ[(wn * 32 + lr) * 136 + kc];
        s16x8 q1 = *(const s16x8*)&sQ[(wn * 32 + 16 + lr) * 136 + kc];
        s16x8 u0 = *(const s16x8*)&sT[(wn * 32 + lr) * 136 + kc];
        s16x8 u1 = *(const s16x8*)&sT[(wn * 32 + 16 + lr) * 136 + kc];
        accA[0][0] = MFMA_BF16(a0, q0, accA[0][0]);
        accA[0][1] = MFMA_BF16(a0, q1, accA[0][1]);
        accA[1][0] = MFMA_BF16(a1, q0, accA[1][0]);
        accA[1][1] = MFMA_BF16(a1, q1, accA[1][1]);
        accB[0][0] = MFMA_BF16(a0, u0, accB[0][0]);
        accB[0][1] = MFMA_BF16(a0, u1, accB[0][1]);
        accB[1][0] = MFMA_BF16(a1, u0, accB[1][0]);
        accB[1][1] = MFMA_BF16(a1, u1, accB[1][1]);
    }

    #pragma unroll
    for (int mr = 0; mr < 2; mr++) {
        #pragma unroll
        for (int reg = 0; reg < 4; reg++) {
            int t = t0 + wm * 32 + mr * 16 + lg * 4 + reg;
            const u16* Cp = Cbf + ((size_t)b * TT + t) * DD;
            float* op = out + ((size_t)b * TT + t) * (4 * DD);
            #pragma unroll
            for (int nr = 0; nr < 2; nr++) {
                int d = d0 + wn * 32 + nr * 16 + lr;
                float cv = bf2f(Cp[d]);
                float av = accA[mr][nr][reg];
                float bv = accB[mr][nr][reg];
                op[d]          = cv;
                op[DD + d]     = av;
                op[2 * DD + d] = cv * av;
                op[3 * DD + d] = cv * bv;
            }
        }
    }
}

// ---------------------------------------------------------------------------
extern "C" void kernel_launch(void* const* d_in, const int* in_sizes, int n_in,
                              void* d_out, int out_size, void* d_ws, size_t ws_size,
                              hipStream_t stream) {
    const float* C = (const float*)d_in[0];
    const float* Q = (const float*)d_in[1];
    const float* w = (const float*)d_in[2];
    float* out = (float*)d_out;
    float* p = (float*)d_ws;

    u16* Xg  = (u16*)p;     p += (size_t)BB * TT * JJ / 2;   // 8.4 MB (X*rowrcp)
    u16* Xt  = (u16*)p;     p += (size_t)BB * JJ * TT / 2;   // 8.4 MB (raw X)
    u16* Cbf = (u16*)p;     p += (size_t)BB * TT * DD / 2;   // 16.8 MB
    u16* Qt  = (u16*)p;     p += (size_t)BB * DD * JJ / 2;
    u16* Tt  = (u16*)p;     p += (size_t)BB * DD * JJ / 2;
    float* rowmax = p;      p += BB * TT;
    float* pm     = p;      p += BB * 16;
    float* ps     = p;      p += (size_t)BB * 16 * JJ;

    k_S     <<<dim3(16 * BB), dim3(256), 0, stream>>>(C, Q, w, Xg, Xt, Cbf, Qt, rowmax, pm, ps);
    k_tmp   <<<dim3(8 * BB), dim3(256), 0, stream>>>(Xt, Cbf, rowmax, pm, ps, Tt);
    k_out   <<<dim3(64 * BB), dim3(256), 0, stream>>>(Xg, Qt, Tt, Cbf, out);
}

// Round 13
// 82.600 us; speedup vs baseline: 1.0573x; 1.0129x over previous
//
#include <hip/hip_runtime.h>
#include <math.h>

#define BB 32
#define TT 1024
#define JJ 128
#define DD 256

typedef unsigned short u16;
typedef short s16x8 __attribute__((ext_vector_type(8)));
typedef float f32x4 __attribute__((ext_vector_type(4)));

#define MFMA_BF16(a, b, c) __builtin_amdgcn_mfma_f32_16x16x32_bf16((a), (b), (c), 0, 0, 0)

__device__ inline u16 f2bf(float f) {
    unsigned int u = __float_as_uint(f);
    u += 0x7FFFu + ((u >> 16) & 1u);
    return (u16)(u >> 16);
}
__device__ inline float bf2f(u16 h) {
    return __uint_as_float(((unsigned int)h) << 16);
}

// ---------------------------------------------------------------------------
// K2 (split-bf16 MFMA): S = ch + qu + (C*w_hu)·Q^T via hi/lo decomposition.
// Self-contained: B staged from fp32 Q inline (hi/lo + qu dot); ch inline;
// emits Cbf, Xg (= X·rowrcp, pre-scaled for k_out), Xt (raw X for k_tmp),
// Qt (bx==kc/64 transpose of staged Bh).
// id = bx*32 + b -> id%8 = b%8 (XCD owns batch).
// ---------------------------------------------------------------------------
__global__ __launch_bounds__(256) void k_S(const float* __restrict__ C,
                                           const float* __restrict__ Q,
                                           const float* __restrict__ w,
                                           u16* __restrict__ Xg,
                                           u16* __restrict__ Xt,
                                           u16* __restrict__ Cbf,
                                           u16* __restrict__ Qt,
                                           float* __restrict__ rowmax,
                                           float* __restrict__ pm,
                                           float* __restrict__ ps) {
    const int id = blockIdx.x;
    const int b  = id & 31;
    const int bx = id >> 5;
    const int t0 = bx * 64;
    const int tid = threadIdx.x;

    union SMem {
        struct { u16 Ah[64 * 72]; u16 Al[64 * 72]; u16 Bh[128 * 72]; u16 Bl[128 * 72]; } g;
        struct { float S[64 * 132]; float RM[64]; float W[4]; float ER[64]; float PS2[256]; } e;
    };
    __shared__ __align__(16) SMem sm;
    __shared__ float sCH[64];
    __shared__ float sQU[128];

    const float* whu = w + 2 * DD;
    const float* Cb  = C + ((size_t)b * TT + t0) * DD;
    const float* Qb  = Q + (size_t)b * JJ * DD;

    const int lane = tid & 63, wv = tid >> 6;
    const int wm = wv >> 1, wn = wv & 1;
    const int lr = lane & 15, lg = lane >> 4;

    f32x4 zero4 = {0.f, 0.f, 0.f, 0.f};
    f32x4 acc[2][4];
    #pragma unroll
    for (int m = 0; m < 2; m++)
        #pragma unroll
        for (int n = 0; n < 4; n++) acc[m][n] = zero4;

    const int tA = tid >> 2, sA = (tid & 3) * 16;
    const int jB = tid >> 1, sB = (tid & 1) * 32;
    float chdot = 0.f;
    float qdot  = 0.f;

    for (int kc = 0; kc < DD; kc += 64) {
        __syncthreads();
        {   // stage A: (C*w_hu)[64t][64k] -> hi/lo bf16; ch dot; Cbf write
            const float* cp  = Cb + (size_t)tA * DD + kc + sA;
            const float* wp  = whu + kc + sA;
            const float* whp = w + kc + sA;
            float cc[16], ww[16], wh[16];
            #pragma unroll
            for (int q = 0; q < 4; q++) {
                *(float4*)&cc[q * 4] = *(const float4*)(cp + q * 4);
                *(float4*)&ww[q * 4] = *(const float4*)(wp + q * 4);
                *(float4*)&wh[q * 4] = *(const float4*)(whp + q * 4);
            }
            u16 hi16[16], lo16[16], cb16[16];
            #pragma unroll
            for (int u = 0; u < 16; u++) {
                chdot += cc[u] * wh[u];
                cb16[u] = f2bf(cc[u]);
                float v = cc[u] * ww[u];
                u16 h = f2bf(v);
                hi16[u] = h;
                lo16[u] = f2bf(v - bf2f(h));
            }
            u16* cbp = &Cbf[((size_t)b * TT + t0 + tA) * DD + kc + sA];
            *(uint4*)&cbp[0] = *(uint4*)&cb16[0];
            *(uint4*)&cbp[8] = *(uint4*)&cb16[8];
            int o = tA * 72 + sA;
            *(uint4*)&sm.g.Ah[o]     = *(uint4*)&hi16[0];
            *(uint4*)&sm.g.Ah[o + 8] = *(uint4*)&hi16[8];
            *(uint4*)&sm.g.Al[o]     = *(uint4*)&lo16[0];
            *(uint4*)&sm.g.Al[o + 8] = *(uint4*)&lo16[8];
        }
        {   // stage B: Q[128j][64k] fp32 -> hi/lo bf16; qu dot inline
            const float* qp  = Qb + (size_t)jB * DD + kc + sB;
            const float* wup = w + DD + kc + sB;
            float qq[32], wu[32];
            #pragma unroll
            for (int q = 0; q < 8; q++) {
                *(float4*)&qq[q * 4] = *(const float4*)(qp + q * 4);
                *(float4*)&wu[q * 4] = *(const float4*)(wup + q * 4);
            }
            u16 h16[32], l16[32];
            #pragma unroll
            for (int u = 0; u < 32; u++) {
                qdot += qq[u] * wu[u];
                u16 h = f2bf(qq[u]);
                h16[u] = h;
                l16[u] = f2bf(qq[u] - bf2f(h));
            }
            uint4* dh = (uint4*)&sm.g.Bh[jB * 72 + sB];
            uint4* dl = (uint4*)&sm.g.Bl[jB * 72 + sB];
            #pragma unroll
            for (int q = 0; q < 4; q++) { dh[q] = *(uint4*)&h16[q * 8]; dl[q] = *(uint4*)&l16[q * 8]; }
        }
        __syncthreads();
        #pragma unroll
        for (int ks = 0; ks < 2; ks++) {
            const int ko = ks * 32 + lg * 8;
            s16x8 ah[2], al[2], bh[4], bl[4];
            #pragma unroll
            for (int m = 0; m < 2; m++) {
                ah[m] = *(const s16x8*)&sm.g.Ah[(wm * 32 + m * 16 + lr) * 72 + ko];
                al[m] = *(const s16x8*)&sm.g.Al[(wm * 32 + m * 16 + lr) * 72 + ko];
            }
            #pragma unroll
            for (int n = 0; n < 4; n++) {
                bh[n] = *(const s16x8*)&sm.g.Bh[(wn * 64 + n * 16 + lr) * 72 + ko];
                bl[n] = *(const s16x8*)&sm.g.Bl[(wn * 64 + n * 16 + lr) * 72 + ko];
            }
            #pragma unroll
            for (int m = 0; m < 2; m++)
                #pragma unroll
                for (int n = 0; n < 4; n++) {
                    f32x4 t = acc[m][n];
                    t = MFMA_BF16(ah[m], bh[n], t);
                    t = MFMA_BF16(ah[m], bl[n], t);
                    t = MFMA_BF16(al[m], bh[n], t);
                    acc[m][n] = t;
                }
        }
        // Qt emission: block bx == kc/64 transposes Bh [128j][64k] -> Qt [d][j]
        if (bx == (kc >> 6)) {
            int dloc = tid >> 2;
            int j0 = (tid & 3) * 32;
            u16 qb[32];
            #pragma unroll
            for (int u = 0; u < 32; u++) qb[u] = sm.g.Bh[(j0 + u) * 72 + dloc];
            u16* qtp = &Qt[((size_t)b * DD + kc + dloc) * JJ + j0];
            #pragma unroll
            for (int q = 0; q < 4; q++) *(uint4*)&qtp[q * 8] = *(uint4*)&qb[q * 8];
        }
    }

    // finalize ch and qu
    chdot += __shfl_xor(chdot, 1, 64);
    chdot += __shfl_xor(chdot, 2, 64);
    if ((tid & 3) == 0) sCH[tid >> 2] = chdot;
    float qd = qdot + __shfl_xor(qdot, 1, 64);
    if ((tid & 1) == 0) sQU[tid >> 1] = qd;

    // ---- epilogue ----
    __syncthreads();
    #pragma unroll
    for (int m = 0; m < 2; m++) {
        int row0 = wm * 32 + m * 16 + lg * 4;
        #pragma unroll
        for (int n = 0; n < 4; n++) {
            int col = wn * 64 + n * 16 + lr;
            float qv = sQU[col];
            #pragma unroll
            for (int reg = 0; reg < 4; reg++)
                sm.e.S[(row0 + reg) * 132 + col] = acc[m][n][reg] + sCH[row0 + reg] + qv;
        }
    }
    __syncthreads();
    {   // pass 1: row stats + in-place exp (S -> X fp32) + Xg = X*rowrcp direct
        int r = tid >> 2, s = tid & 3;
        float v[32];
        float* Sr = &sm.e.S[r * 132 + s * 32];
        #pragma unroll
        for (int q = 0; q < 8; q++) *(float4*)&v[q * 4] = *(const float4*)&Sr[q * 4];
        float mx = v[0];
        #pragma unroll
        for (int u = 1; u < 32; u++) mx = fmaxf(mx, v[u]);
        mx = fmaxf(mx, __shfl_xor(mx, 1, 64));
        mx = fmaxf(mx, __shfl_xor(mx, 2, 64));
        float sum = 0.f;
        #pragma unroll
        for (int u = 0; u < 32; u++) { v[u] = __expf(v[u] - mx); sum += v[u]; }
        sum += __shfl_xor(sum, 1, 64);
        sum += __shfl_xor(sum, 2, 64);
        #pragma unroll
        for (int q = 0; q < 8; q++) *(float4*)&Sr[q * 4] = *(const float4*)&v[q * 4];
        float rcp = 1.0f / sum;
        u16 xp[32];
        #pragma unroll
        for (int u = 0; u < 32; u++) xp[u] = f2bf(v[u] * rcp);
        u16* xgp = &Xg[((size_t)b * TT + t0 + r) * JJ + s * 32];
        #pragma unroll
        for (int q = 0; q < 4; q++) *(uint4*)&xgp[q * 8] = *(uint4*)&xp[q * 8];
        if (s == 0) {
            sm.e.RM[r] = mx;
            rowmax[(size_t)b * TT + t0 + r] = mx;
        }
        float wmx = mx;
        wmx = fmaxf(wmx, __shfl_xor(wmx, 4, 64));
        wmx = fmaxf(wmx, __shfl_xor(wmx, 8, 64));
        wmx = fmaxf(wmx, __shfl_xor(wmx, 16, 64));
        wmx = fmaxf(wmx, __shfl_xor(wmx, 32, 64));
        if (lane == 0) sm.e.W[wv] = wmx;
    }
    __syncthreads();
    const float Mb = fmaxf(fmaxf(sm.e.W[0], sm.e.W[1]), fmaxf(sm.e.W[2], sm.e.W[3]));
    if (tid < 64) sm.e.ER[tid] = __expf(sm.e.RM[tid] - Mb);
    // Xt write [j][t] (raw X for k_tmp): thread = (j, 32-t seg)
    {
        int j = tid & 127, seg = tid >> 7;
        u16 xb[32];
        #pragma unroll
        for (int k = 0; k < 32; k++)
            xb[k] = f2bf(sm.e.S[(seg * 32 + k) * 132 + j]);
        u16* xtp = &Xt[((size_t)b * JJ + j) * TT + t0 + seg * 32];
        #pragma unroll
        for (int q = 0; q < 4; q++) *(uint4*)&xtp[q * 8] = *(uint4*)&xb[q * 8];
    }
    __syncthreads();
    {   // column partials: pure fma against ER (no exp)
        int j = tid & 127, h = tid >> 7;
        float cs = 0.f;
        #pragma unroll
        for (int k = 0; k < 32; k++)
            cs = fmaf(sm.e.S[(h * 32 + k) * 132 + j], sm.e.ER[h * 32 + k], cs);
        sm.e.PS2[h * 128 + j] = cs;
    }
    __syncthreads();
    if (tid < 128) ps[((size_t)b * 16 + bx) * JJ + tid] = sm.e.PS2[tid] + sm.e.PS2[128 + tid];
    if (tid == 0)  pm[b * 16 + bx] = Mb;
}

// ---------------------------------------------------------------------------
// K4 (MFMA): Tt[d,j] = ec[j] * sum_t X[t,j] * (er[t]*C[t,d]).
// 16-way d-split (512 blocks = 2 blocks/CU, 8 waves: doubles latency hiding
// vs the 8-way split's 1 block/CU). G-staging = pure uint4 copies from Xt;
// er folded into the small 16-d C'-staging; ec in the epilogue.
// id = dh*32 + b -> id%8 = b%8 (XCD owns batch; X/ Cbf L2-resident).
// ---------------------------------------------------------------------------
__global__ __launch_bounds__(256) void k_tmp(const u16* __restrict__ Xt,
                                             const u16* __restrict__ Cbf,
                                             const float* __restrict__ rowmax,
                                             const float* __restrict__ pm,
                                             const float* __restrict__ ps,
                                             u16* __restrict__ Tt) {
    const int id = blockIdx.x;
    const int b = id & 31, dh = id >> 5;          // dh in 0..15
    const int d0 = dh * 16;
    const int tid = threadIdx.x;
    __shared__ __align__(16) u16 sG[128 * 72];    // [j][t] stride 72 (pure X)
    __shared__ __align__(16) u16 sCt[16 * 72];    // [d][t] stride 72 (er*C)
    __shared__ float sER[1024];
    __shared__ float sEC[128];
    __shared__ float sPE[16];
    __shared__ float sW2[4];
    const int lane = tid & 63, wv = tid >> 6;

    {   // K_b = max rowmax over batch; er, ec = 1/colsum(K-ref)
        float4 rm4 = *(const float4*)&rowmax[(size_t)b * TT + tid * 4];
        float km = fmaxf(fmaxf(rm4.x, rm4.y), fmaxf(rm4.z, rm4.w));
        #pragma unroll
        for (int off = 1; off < 64; off <<= 1) km = fmaxf(km, __shfl_xor(km, off, 64));
        if (lane == 0) sW2[wv] = km;
        __syncthreads();
        const float K = fmaxf(fmaxf(sW2[0], sW2[1]), fmaxf(sW2[2], sW2[3]));
        float4 e4;
        e4.x = __expf(rm4.x - K);
        e4.y = __expf(rm4.y - K);
        e4.z = __expf(rm4.z - K);
        e4.w = __expf(rm4.w - K);
        *(float4*)&sER[tid * 4] = e4;
        if (tid < 16) sPE[tid] = __expf(pm[b * 16 + tid] - K);
        __syncthreads();
        if (tid < 128) {
            float cy = 0.f;
            #pragma unroll
            for (int blk = 0; blk < 16; blk++)
                cy = fmaf(ps[((size_t)b * 16 + blk) * JJ + tid], sPE[blk], cy);
            sEC[tid] = 1.0f / cy;
        }
    }

    const int lr = lane & 15, lg = lane >> 4;
    f32x4 zero4 = {0.f, 0.f, 0.f, 0.f};
    f32x4 acc[2];
    acc[0] = zero4; acc[1] = zero4;

    const int gj = tid >> 1, gs = (tid & 1) * 32;     // G: j row, 32-t seg
    const int ct = tid & 63, cg = (tid >> 6) * 4;     // Ct: t row, 4-d seg

    for (int tt = 0; tt < TT; tt += 64) {
        __syncthreads();
        {   // stage G = X (pure uint4 copies from Xt)
            const u16* xtp = &Xt[((size_t)b * JJ + gj) * TT + tt + gs];
            u16* gp = &sG[gj * 72 + gs];
            #pragma unroll
            for (int q = 0; q < 4; q++) *(uint4*)&gp[q * 8] = *(const uint4*)&xtp[q * 8];
        }
        {   // stage C' = er[t]*C[t,d]  (16 d columns of this block)
            float e = sER[tt + ct];
            ushort4 cv = *(const ushort4*)&Cbf[((size_t)b * TT + tt + ct) * DD + d0 + cg];
            const u16* cp = (const u16*)&cv;
            #pragma unroll
            for (int u = 0; u < 4; u++) sCt[(cg + u) * 72 + ct] = f2bf(bf2f(cp[u]) * e);
        }
        __syncthreads();
        #pragma unroll
        for (int ks = 0; ks < 2; ks++) {
            int ko = ks * 32 + lg * 8;
            s16x8 a0 = *(const s16x8*)&sG[(wv * 32 + lr) * 72 + ko];
            s16x8 a1 = *(const s16x8*)&sG[(wv * 32 + 16 + lr) * 72 + ko];
            s16x8 b0 = *(const s16x8*)&sCt[lr * 72 + ko];
            acc[0] = MFMA_BF16(a0, b0, acc[0]);
            acc[1] = MFMA_BF16(a1, b0, acc[1]);
        }
    }
    #pragma unroll
    for (int mr = 0; mr < 2; mr++)
        #pragma unroll
        for (int reg = 0; reg < 4; reg++) {
            int j = wv * 32 + mr * 16 + lg * 4 + reg;
            int d = d0 + lr;
            Tt[((size_t)b * DD + d) * JJ + j] = f2bf(acc[mr][reg] * sEC[j]);
        }
}

// ---------------------------------------------------------------------------
// K5 (MFMA): A = Xg·Q, Bm = Xg·tmp (Xg pre-scaled by rowrcp);
// out = [C, A, C*A, C*Bm]; C from Cbf. id = k*32 + b -> id%8 = b%8.
// ---------------------------------------------------------------------------
__global__ __launch_bounds__(256) void k_out(const u16* __restrict__ Xg,
                                             const u16* __restrict__ Qt,
                                             const u16* __restrict__ Tt,
                                             const u16* __restrict__ Cbf,
                                             float* __restrict__ out) {
    const int id = blockIdx.x;
    const int b = id & 31, k = id >> 5;
    const int dc = k & 3, tc = k >> 2;
    const int t0 = tc * 64, d0 = dc * 64;
    const int tid = threadIdx.x;
    __shared__ __align__(16) u16 sX[64 * 136];
    __shared__ __align__(16) u16 sQ[64 * 136];
    __shared__ __align__(16) u16 sT[64 * 136];
    const size_t xbase = ((size_t)b * TT + t0) * JJ;
    const size_t qbase = ((size_t)b * DD + d0) * JJ;
    #pragma unroll
    for (int i = 0; i < 4; i++) {
        int c = tid + 256 * i;
        int row = c >> 4, col = (c & 15) * 8;
        int lo = row * 136 + col;
        *(uint4*)&sX[lo] = *(const uint4*)&Xg[xbase + (size_t)row * JJ + col];
        *(uint4*)&sQ[lo] = *(const uint4*)&Qt[qbase + (size_t)row * JJ + col];
        *(uint4*)&sT[lo] = *(const uint4*)&Tt[qbase + (size_t)row * JJ + col];
    }
    __syncthreads();
    const int lane = tid & 63, wv = tid >> 6;
    const int wm = wv >> 1, wn = wv & 1;
    const int lr = lane & 15, lg = lane >> 4;
    f32x4 zero4 = {0.f, 0.f, 0.f, 0.f};
    f32x4 accA[2][2], accB[2][2];
    #pragma unroll
    for (int mr = 0; mr < 2; mr++)
        #pragma unroll
        for (int nr = 0; nr < 2; nr++) { accA[mr][nr] = zero4; accB[mr][nr] = zero4; }

    #pragma unroll
    for (int ks = 0; ks < 4; ks++) {
        int kc = ks * 32 + lg * 8;
        s16x8 a0 = *(const s16x8*)&sX[(wm * 32 + lr) * 136 + kc];
        s16x8 a1 = *(const s16x8*)&sX[(wm * 32 + 16 + lr) * 136 + kc];
        s16x8 q0 = *(const s16x8*)&sQ[(wn * 32 + lr) * 136 + kc];
        s16x8 q1 = *(const s16x8*)&sQ[(wn * 32 + 16 + lr) * 136 + kc];
        s16x8 u0 = *(const s16x8*)&sT[(wn * 32 + lr) * 136 + kc];
        s16x8 u1 = *(const s16x8*)&sT[(wn * 32 + 16 + lr) * 136 + kc];
        accA[0][0] = MFMA_BF16(a0, q0, accA[0][0]);
        accA[0][1] = MFMA_BF16(a0, q1, accA[0][1]);
        accA[1][0] = MFMA_BF16(a1, q0, accA[1][0]);
        accA[1][1] = MFMA_BF16(a1, q1, accA[1][1]);
        accB[0][0] = MFMA_BF16(a0, u0, accB[0][0]);
        accB[0][1] = MFMA_BF16(a0, u1, accB[0][1]);
        accB[1][0] = MFMA_BF16(a1, u0, accB[1][0]);
        accB[1][1] = MFMA_BF16(a1, u1, accB[1][1]);
    }

    #pragma unroll
    for (int mr = 0; mr < 2; mr++) {
        #pragma unroll
        for (int reg = 0; reg < 4; reg++) {
            int t = t0 + wm * 32 + mr * 16 + lg * 4 + reg;
            const u16* Cp = Cbf + ((size_t)b * TT + t) * DD;
            float* op = out + ((size_t)b * TT + t) * (4 * DD);
            #pragma unroll
            for (int nr = 0; nr < 2; nr++) {
                int d = d0 + wn * 32 + nr * 16 + lr;
                float cv = bf2f(Cp[d]);
                float av = accA[mr][nr][reg];
                float bv = accB[mr][nr][reg];
                op[d]          = cv;
                op[DD + d]     = av;
                op[2 * DD + d] = cv * av;
                op[3 * DD + d] = cv * bv;
            }
        }
    }
}

// ---------------------------------------------------------------------------
extern "C" void kernel_launch(void* const* d_in, const int* in_sizes, int n_in,
                              void* d_out, int out_size, void* d_ws, size_t ws_size,
                              hipStream_t stream) {
    const float* C = (const float*)d_in[0];
    const float* Q = (const float*)d_in[1];
    const float* w = (const float*)d_in[2];
    float* out = (float*)d_out;
    float* p = (float*)d_ws;

    u16* Xg  = (u16*)p;     p += (size_t)BB * TT * JJ / 2;   // 8.4 MB (X*rowrcp)
    u16* Xt  = (u16*)p;     p += (size_t)BB * JJ * TT / 2;   // 8.4 MB (raw X)
    u16* Cbf = (u16*)p;     p += (size_t)BB * TT * DD / 2;   // 16.8 MB
    u16* Qt  = (u16*)p;     p += (size_t)BB * DD * JJ / 2;
    u16* Tt  = (u16*)p;     p += (size_t)BB * DD * JJ / 2;
    float* rowmax = p;      p += BB * TT;
    float* pm     = p;      p += BB * 16;
    float* ps     = p;      p += (size_t)BB * 16 * JJ;

    k_S     <<<dim3(16 * BB), dim3(256), 0, stream>>>(C, Q, w, Xg, Xt, Cbf, Qt, rowmax, pm, ps);
    k_tmp   <<<dim3(16 * BB), dim3(256), 0, stream>>>(Xt, Cbf, rowmax, pm, ps, Tt);
    k_out   <<<dim3(64 * BB), dim3(256), 0, stream>>>(Xg, Qt, Tt, Cbf, out);
}